// Round 5
// baseline (414.933 us; speedup 1.0000x reference)
//
#include <hip/hip_runtime.h>
#include <hip/hip_bf16.h>

// B=2, S=768, H=768, NH=12, D=64, NKEY=9216. Output fp32 [B][S][NH][D].
// Round 5: flash re-gridded to 128-thread blocks (1152 blocks, XCD-local id
// swizzle: same (b,c) K/V chunk -> same XCD L2), per-wave inner loop identical
// to verified r4 (32x32x16 transposed-S, P^T in regs). gemm_core gains
// double-buffered LDS (1 barrier/slab) + register prefetch.

typedef __bf16 bf16_t;
typedef __bf16 bf16x8 __attribute__((ext_vector_type(8)));
typedef float f32x4 __attribute__((ext_vector_type(4)));
typedef float f32x16 __attribute__((ext_vector_type(16)));
typedef unsigned long long u64;

#define MFMA16(a, b, c) __builtin_amdgcn_mfma_f32_16x16x32_bf16((a), (b), (c), 0, 0, 0)
#define MFMA32(a, b, c) __builtin_amdgcn_mfma_f32_32x32x16_bf16((a), (b), (c), 0, 0, 0)
#define LOG2E 1.44269504088896340736f
#define SCALE_Q 0.18033688011112042f /* (1/8) * log2(e) */
#define SHIFT_C 8.0f                 /* fixed softmax shift (base-2 units) */
#define NSPLIT 8
#define KCHUNK 1152 /* 9216/8, 18 iters of 64 */

// ---------------- transpose + convert: Wt[n][k] = (bf16)W[k][n], 768x768 ----
__global__ __launch_bounds__(256) void transpose_cvt3(const float* __restrict__ Wq,
                                                      const float* __restrict__ Wk,
                                                      const float* __restrict__ Wv,
                                                      bf16_t* __restrict__ Wt) {
  __shared__ float t[32][33];
  const float* W = (blockIdx.z == 0) ? Wq : (blockIdx.z == 1) ? Wk : Wv;
  bf16_t* o = Wt + (size_t)blockIdx.z * 589824;
  const int bx = blockIdx.x * 32;
  const int by = blockIdx.y * 32;
  const int tx = threadIdx.x, ty = threadIdx.y;
#pragma unroll
  for (int i = 0; i < 32; i += 8) t[ty + i][tx] = W[(bx + ty + i) * 768 + by + tx];
  __syncthreads();
#pragma unroll
  for (int i = 0; i < 32; i += 8)
    o[(by + ty + i) * 768 + bx + tx] = (bf16_t)t[tx][ty + i];
}

// ---------------- canonical C[M][N] = A[M][K] * B[N][K]^T, bf16 MFMA --------
__device__ __forceinline__ bf16x8 cvt8u(const uint4 x, const uint4 y) {
  union { uint4 u; float f[4]; } a, b;
  a.u = x; b.u = y;
  bf16x8 o;
  o[0] = (bf16_t)a.f[0]; o[1] = (bf16_t)a.f[1];
  o[2] = (bf16_t)a.f[2]; o[3] = (bf16_t)a.f[3];
  o[4] = (bf16_t)b.f[0]; o[5] = (bf16_t)b.f[1];
  o[6] = (bf16_t)b.f[2]; o[7] = (bf16_t)b.f[3];
  return o;
}

// Double-buffered LDS, one barrier per 64-deep K slab, register prefetch.
template <int BM, int BN, bool AF32, bool BF32, typename EPI>
__device__ __forceinline__ void gemm_core(char* __restrict__ smem,
                                          const void* __restrict__ Ap, int lda,
                                          const void* __restrict__ Bp, int ldb,
                                          int K, int m0, int n0, EPI epi) {
  constexpr int MT = BM / 32;
  constexpr int NT = BN / 32;
  constexpr int AC = BM * 8 / 256;  // 16B chunks per thread (A)
  constexpr int BC = BN * 8 / 256;
  constexpr int HALF = (BM + BN) * 144;

  const int tid = threadIdx.x;
  const int lane = tid & 63;
  const int w = tid >> 6;
  const int l15 = lane & 15, quad = lane >> 4;
  const int wm = (w & 1) * (BM / 2);
  const int wn = (w >> 1) * (BN / 2);

  uint4 pa[AC][2], pb[BC][2];

  auto loadA = [&](int kk) {
#pragma unroll
    for (int i = 0; i < AC; ++i) {
      const int cidx = tid + i * 256, r = cidx >> 3, ch = cidx & 7;
      if constexpr (AF32) {
        const float* s = (const float*)Ap + (size_t)(m0 + r) * lda + kk + ch * 8;
        pa[i][0] = *(const uint4*)s;
        pa[i][1] = *(const uint4*)(s + 4);
      } else {
        const bf16_t* s = (const bf16_t*)Ap + (size_t)(m0 + r) * lda + kk + ch * 8;
        pa[i][0] = *(const uint4*)s;
      }
    }
  };
  auto loadB = [&](int kk) {
#pragma unroll
    for (int i = 0; i < BC; ++i) {
      const int cidx = tid + i * 256, r = cidx >> 3, ch = cidx & 7;
      if constexpr (BF32) {
        const float* s = (const float*)Bp + (size_t)(n0 + r) * ldb + kk + ch * 8;
        pb[i][0] = *(const uint4*)s;
        pb[i][1] = *(const uint4*)(s + 4);
      } else {
        const bf16_t* s = (const bf16_t*)Bp + (size_t)(n0 + r) * ldb + kk + ch * 8;
        pb[i][0] = *(const uint4*)s;
      }
    }
  };
  auto store = [&](char* base) {
    char* sA = base;
    char* sB = base + BM * 144;
#pragma unroll
    for (int i = 0; i < AC; ++i) {
      const int cidx = tid + i * 256, r = cidx >> 3, ch = cidx & 7;
      if constexpr (AF32)
        *(bf16x8*)(sA + r * 144 + ch * 16) = cvt8u(pa[i][0], pa[i][1]);
      else
        *(uint4*)(sA + r * 144 + ch * 16) = pa[i][0];
    }
#pragma unroll
    for (int i = 0; i < BC; ++i) {
      const int cidx = tid + i * 256, r = cidx >> 3, ch = cidx & 7;
      if constexpr (BF32)
        *(bf16x8*)(sB + r * 144 + ch * 16) = cvt8u(pb[i][0], pb[i][1]);
      else
        *(uint4*)(sB + r * 144 + ch * 16) = pb[i][0];
    }
  };

  const f32x4 fzero = {0.f, 0.f, 0.f, 0.f};
  f32x4 acc[MT][NT];
#pragma unroll
  for (int i = 0; i < MT; ++i)
#pragma unroll
    for (int j = 0; j < NT; ++j) acc[i][j] = fzero;

  const int NS = K / 64;
  loadA(0);
  loadB(0);
  store(smem);

  for (int t = 0; t < NS; ++t) {
    char* base = smem + (t & 1) * HALF;
    char* sA = base;
    char* sB = base + BM * 144;
    __syncthreads();
    if (t + 1 < NS) {
      loadA((t + 1) * 64);
      loadB((t + 1) * 64);
    }
#pragma unroll
    for (int ks = 0; ks < 2; ++ks) {
      bf16x8 af[MT], bfr[NT];
#pragma unroll
      for (int i = 0; i < MT; ++i)
        af[i] = *(const bf16x8*)(sA + (wm + i * 16 + l15) * 144 + ks * 64 + quad * 16);
#pragma unroll
      for (int j = 0; j < NT; ++j)
        bfr[j] = *(const bf16x8*)(sB + (wn + j * 16 + l15) * 144 + ks * 64 + quad * 16);
#pragma unroll
      for (int i = 0; i < MT; ++i)
#pragma unroll
        for (int j = 0; j < NT; ++j) acc[i][j] = MFMA16(af[i], bfr[j], acc[i][j]);
    }
    if (t + 1 < NS) store(smem + ((t + 1) & 1) * HALF);
  }
#pragma unroll
  for (int i = 0; i < MT; ++i)
#pragma unroll
    for (int j = 0; j < NT; ++j)
#pragma unroll
      for (int p = 0; p < 4; ++p)
        epi(m0 + wm + i * 16 + quad * 4 + p, n0 + wn + j * 16 + l15, acc[i][j][p]);
}

// Merged QKV projections (64x64 tiles, dbuf).
__global__ __launch_bounds__(256) void gemm_qkv(const float* __restrict__ hid,
                                                const bf16_t* __restrict__ wT,
                                                const float* __restrict__ bq,
                                                const float* __restrict__ bk,
                                                const float* __restrict__ bv,
                                                bf16_t* __restrict__ q,
                                                bf16_t* __restrict__ ktvt) {
  __shared__ __align__(16) char smem[2 * (64 + 64) * 144];
  if (blockIdx.y < 12) {
    const int m0 = blockIdx.x * 64, n0 = blockIdx.y * 64;
    auto epi = [=](int m, int n, float v) {
      const int b = m / 768, s = m - b * 768;
      const int h = n >> 6, d = n & 63;
      q[((size_t)((b * 12 + h) * 768 + s) << 6) + d] = (bf16_t)((v + bq[n]) * SCALE_Q);
    };
    gemm_core<64, 64, true, false>(smem, hid, 768, wT, 768, 768, m0, n0, epi);
  } else {
    const int m0 = blockIdx.x * 64, n0 = (blockIdx.y - 12) * 64;
    auto epi = [=](int m, int n, float v) {
      const float bias = (m < 768) ? bk[m] : bv[m - 768];
      ktvt[(size_t)m * 1536 + n] = (bf16_t)(v + bias);
    };
    gemm_core<64, 64, false, true>(smem, wT + 589824, 768, hid, 768, 768, m0, n0, epi);
  }
}

// Merged memory GEMMs (64x64 tiles, dbuf).
__global__ __launch_bounds__(256) void gemm_mem(const float* __restrict__ memk,
                                                const float* __restrict__ memv,
                                                const bf16_t* __restrict__ ktvt,
                                                bf16_t* __restrict__ kc,
                                                bf16_t* __restrict__ vct) {
  __shared__ __align__(16) char smem[2 * (64 + 64) * 144];
  const int z = blockIdx.z, b = z / 12, h = z - (z / 12) * 12;
  if (blockIdx.y == 0) {
    const int m0 = blockIdx.x * 64;
    const float* A = memk + (size_t)h * 589824;
    const bf16_t* B = ktvt + (size_t)(h * 64) * 1536 + b * 768;
    bf16_t* outp = kc + (size_t)b * 589824 + (size_t)h * 768 * 64;
    auto epi = [=](int m, int n, float v) { outp[((size_t)m << 6) + n] = (bf16_t)v; };
    gemm_core<64, 64, true, false>(smem, A, 768, B, 1536, 768, m0, 0, epi);
  } else {
    const int n0 = blockIdx.x * 64;
    const bf16_t* A = ktvt + (size_t)(768 + h * 64) * 1536 + b * 768;
    const float* B = memv + (size_t)h * 589824;
    bf16_t* outp = vct + (size_t)b * 589824 + h * 768;
    auto epi = [=](int m, int n, float v) { outp[(size_t)m * 9216 + n] = (bf16_t)v; };
    gemm_core<64, 64, false, true>(smem, A, 1536, B, 768, 768, 0, n0, epi);
  }
}

// ---------------- flash attention, split-K, 32x32 MFMA, transposed-S -------
// 128-thread blocks (2 waves x 64 q-rows). Grid 1-D 1152 with XCD-local id:
// id = (b*8+c) + 16*(h*6+qt) -> same (b,c) K/V chunk lands on one XCD's L2.
// Per-wave math identical to verified r4 kernel.
__global__ __launch_bounds__(128, 3) void flash_attn_split(
    const bf16_t* __restrict__ q, const bf16_t* __restrict__ kc,
    const bf16_t* __restrict__ vct, const float* __restrict__ mask,
    float* __restrict__ part_acc, float* __restrict__ part_l) {
  const int id = blockIdx.x;
  const int c = id & 7, b = (id >> 3) & 1;
  const int rest = id >> 4;  // 0..71
  const int h = rest / 6, qt = rest - h * 6;
  const int tid = threadIdx.x;
  const int w = tid >> 6, lane = tid & 63, l31 = lane & 31, h5 = lane >> 5;

  __shared__ __align__(16) bf16_t kc_s[64 * 72];  // [key][d], 144B rows
  __shared__ __align__(16) bf16_t vt_s[64 * 72];  // [d][key], 144B rows
  __shared__ float w_s[64];

  const bf16_t* kcb = kc + (size_t)b * 589824;
  const bf16_t* vtb = vct + (size_t)b * 589824;
  const float* mkb = mask + b * 9216;

  // Q B-frags, held for the whole kernel
  const int q0 = qt * 128 + w * 64;
  bf16x8 qf[2][4];
#pragma unroll
  for (int nb = 0; nb < 2; ++nb) {
    const bf16_t* qp =
        q + ((size_t)((b * 12 + h) * 768 + q0 + nb * 32 + l31) << 6) + h5 * 8;
#pragma unroll
    for (int kd = 0; kd < 4; ++kd) qf[nb][kd] = *(const bf16x8*)(qp + kd * 16);
  }

  f32x16 o[2][2];
#pragma unroll
  for (int nb = 0; nb < 2; ++nb)
#pragma unroll
    for (int md = 0; md < 2; ++md)
#pragma unroll
      for (int r = 0; r < 16; ++r) o[nb][md][r] = 0.f;
  float rsum[2] = {0.f, 0.f};

  // staging: 1024 16B chunks (512 kc + 512 vt), 8 per thread
  const int k00 = c * KCHUNK;
  uint4 pk[4], pv[4];
#pragma unroll
  for (int i = 0; i < 4; ++i) {
    const int ck = tid + i * 128, r = ck >> 3, ch = ck & 7;
    pk[i] = *(const uint4*)(kcb + ((size_t)(k00 + r) << 6) + ch * 8);
    pv[i] = *(const uint4*)(vtb + (size_t)r * 9216 + k00 + ch * 8);
  }
  float mraw = (tid < 64) ? mkb[k00 + tid] : 0.f;

  for (int t = 0; t < KCHUNK / 64; ++t) {
#pragma unroll
    for (int i = 0; i < 4; ++i) {
      const int ck = tid + i * 128, r = ck >> 3, ch = ck & 7;
      *(uint4*)((char*)kc_s + r * 144 + ch * 16) = pk[i];
      *(uint4*)((char*)vt_s + r * 144 + ch * 16) = pv[i];
    }
    if (tid < 64) w_s[tid] = exp2f(fmaf(mraw, LOG2E, -SHIFT_C));
    __syncthreads();

    if (t + 1 < KCHUNK / 64) {  // prefetch next tile behind compute
      const int k1 = k00 + (t + 1) * 64;
#pragma unroll
      for (int i = 0; i < 4; ++i) {
        const int ck = tid + i * 128, r = ck >> 3, ch = ck & 7;
        pk[i] = *(const uint4*)(kcb + ((size_t)(k1 + r) << 6) + ch * 8);
        pv[i] = *(const uint4*)(vtb + (size_t)r * 9216 + k1 + ch * 8);
      }
      if (tid < 64) mraw = mkb[k1 + tid];
    }

#pragma unroll
    for (int mb = 0; mb < 2; ++mb) {  // 32-key block
      bf16x8 ka[4];
#pragma unroll
      for (int kd = 0; kd < 4; ++kd)
        ka[kd] =
            *(const bf16x8*)((char*)kc_s + (mb * 32 + l31) * 144 + kd * 32 + h5 * 16);
      bf16x8 va[2][2];
#pragma unroll
      for (int md = 0; md < 2; ++md)
#pragma unroll
        for (int tt = 0; tt < 2; ++tt) {
          const char* vp =
              (char*)vt_s + (md * 32 + l31) * 144 + mb * 64 + tt * 32 + h5 * 8;
          union { u64 u[2]; bf16x8 v; } tmp;
          tmp.u[0] = *(const u64*)vp;
          tmp.u[1] = *(const u64*)(vp + 16);
          va[md][tt] = tmp.v;
        }
      float wv[16];
#pragma unroll
      for (int g = 0; g < 4; ++g) {
        const float4 t4 = *(const float4*)(w_s + mb * 32 + h5 * 4 + g * 8);
        wv[g * 4 + 0] = t4.x; wv[g * 4 + 1] = t4.y;
        wv[g * 4 + 2] = t4.z; wv[g * 4 + 3] = t4.w;
      }
#pragma unroll
      for (int nb = 0; nb < 2; ++nb) {
        f32x16 s;
#pragma unroll
        for (int r = 0; r < 16; ++r) s[r] = 0.f;
#pragma unroll
        for (int kd = 0; kd < 4; ++kd) s = MFMA32(ka[kd], qf[nb][kd], s);
        float pw[16];
#pragma unroll
        for (int r = 0; r < 16; ++r) {
          const float pv2 = __builtin_amdgcn_exp2f(s[r]) * wv[r];
          rsum[nb] += pv2;
          pw[r] = pv2;
        }
        bf16x8 pb0, pb1;
#pragma unroll
        for (int j = 0; j < 8; ++j) {
          pb0[j] = (bf16_t)pw[j];
          pb1[j] = (bf16_t)pw[8 + j];
        }
#pragma unroll
        for (int md = 0; md < 2; ++md) {
          o[nb][md] = MFMA32(va[md][0], pb0, o[nb][md]);
          o[nb][md] = MFMA32(va[md][1], pb1, o[nb][md]);
        }
      }
    }
    __syncthreads();
  }

  const float l0 = rsum[0] + __shfl_xor(rsum[0], 32);
  const float l1 = rsum[1] + __shfl_xor(rsum[1], 32);

  const int pidx = ((b * 12 + h) * 6 + qt) * NSPLIT + c;
  float* pacc = part_acc + (size_t)pidx * 8192;
#pragma unroll
  for (int nb = 0; nb < 2; ++nb) {
    const int ql = w * 64 + nb * 32 + l31;
#pragma unroll
    for (int md = 0; md < 2; ++md)
#pragma unroll
      for (int g = 0; g < 4; ++g) {
        float4 v;
        v.x = o[nb][md][g * 4 + 0];
        v.y = o[nb][md][g * 4 + 1];
        v.z = o[nb][md][g * 4 + 2];
        v.w = o[nb][md][g * 4 + 3];
        *(float4*)(pacc + (size_t)ql * 64 + md * 32 + h5 * 4 + g * 8) = v;
      }
  }
  if (h5 == 0) {
    part_l[(size_t)pidx * 128 + w * 64 + l31] = l0;
    part_l[(size_t)pidx * 128 + w * 64 + 32 + l31] = l1;
  }
}

// ---------------- combine split-K partials, normalize, gate, write out -----
__global__ __launch_bounds__(1024) void flash_combine(
    const float* __restrict__ part_acc, const float* __restrict__ part_l,
    const float* __restrict__ gate, float* __restrict__ out) {
  const int qt = blockIdx.x, h = blockIdx.y, b = blockIdx.z;  // grid (6,12,2)
  const int tid = threadIdx.x;
  const int row = tid >> 3, dseg = tid & 7;  // 128 rows, 8 d-elems per thread
  const int base = ((b * 12 + h) * 6 + qt) * NSPLIT;

  float L = 0.f;
#pragma unroll
  for (int ci = 0; ci < NSPLIT; ++ci) L += part_l[(size_t)(base + ci) * 128 + row];

  f32x4 a0 = {0.f, 0.f, 0.f, 0.f}, a1 = {0.f, 0.f, 0.f, 0.f};
#pragma unroll
  for (int ci = 0; ci < NSPLIT; ++ci) {
    const float* p = part_acc + (size_t)(base + ci) * 8192 + row * 64 + dseg * 8;
    const float4 v0 = *(const float4*)p;
    const float4 v1 = *(const float4*)(p + 4);
    a0[0] += v0.x; a0[1] += v0.y; a0[2] += v0.z; a0[3] += v0.w;
    a1[0] += v1.x; a1[1] += v1.y; a1[2] += v1.z; a1[3] += v1.w;
  }
  const float g = 1.f / (1.f + expf(-gate[h]));
  const float sc = g / L;
  float* op =
      out + ((size_t)((b * 768 + qt * 128 + row) * 12 + h) << 6) + dseg * 8;
  float4 w0, w1;
  w0.x = a0[0] * sc; w0.y = a0[1] * sc; w0.z = a0[2] * sc; w0.w = a0[3] * sc;
  w1.x = a1[0] * sc; w1.y = a1[1] * sc; w1.z = a1[2] * sc; w1.w = a1[3] * sc;
  *(float4*)op = w0;
  *(float4*)(op + 4) = w1;
}

extern "C" void kernel_launch(void* const* d_in, const int* in_sizes, int n_in,
                              void* d_out, int out_size, void* d_ws, size_t ws_size,
                              hipStream_t stream) {
  const float* hid  = (const float*)d_in[0];
  const float* mask = (const float*)d_in[1];
  const float* Wq   = (const float*)d_in[2];
  const float* bq   = (const float*)d_in[3];
  const float* Wk   = (const float*)d_in[4];
  const float* bk   = (const float*)d_in[5];
  const float* Wv   = (const float*)d_in[6];
  const float* bv   = (const float*)d_in[7];
  const float* gate = (const float*)d_in[8];
  const float* memk = (const float*)d_in[9];
  const float* memv = (const float*)d_in[10];
  float* out = (float*)d_out;

  // workspace layout (~53.7 MB total, unchanged)
  char* ws = (char*)d_ws;
  bf16_t* wqkvT    = (bf16_t*)(ws);             // [2304][768] bf16
  bf16_t* qb       = (bf16_t*)(ws + 3538944);   // q [2][12][768][64] bf16
  bf16_t* ktvt     = (bf16_t*)(ws + 5898240);   // [1536][1536] bf16
  bf16_t* kcw      = (bf16_t*)(ws + 10616832);  // kc [2][9216][64] bf16
  bf16_t* vct      = (bf16_t*)(ws + 12976128);  // vc^T [2][64][9216] bf16
  float*  part_acc = (float*)(ws + 15335424);   // [1152][128][64] fp32
  float*  part_l   = (float*)(ws + 53084160);   // [1152][128] fp32

  transpose_cvt3<<<dim3(24, 24, 3), dim3(32, 8), 0, stream>>>(Wq, Wk, Wv, wqkvT);
  gemm_qkv<<<dim3(24, 36), 256, 0, stream>>>(hid, wqkvT, bq, bk, bv, qb, ktvt);
  gemm_mem<<<dim3(12, 2, 24), 256, 0, stream>>>(memk, memv, ktvt, kcw, vct);
  flash_attn_split<<<dim3(1152), 128, 0, stream>>>(qb, kcw, vct, mask,
                                                   part_acc, part_l);
  flash_combine<<<dim3(6, 12, 2), 1024, 0, stream>>>(part_acc, part_l, gate, out);
}

// Round 6
// 292.048 us; speedup vs baseline: 1.4208x; 1.4208x over previous
//
#include <hip/hip_runtime.h>
#include <hip/hip_bf16.h>

// B=2, S=768, H=768, NH=12, D=64, NKEY=9216. Output fp32 [B][S][NH][D].
// Round 6: r5's 128-thread flash blocks but (a) __launch_bounds__(128,2) so
// nothing spills (r5's (128,3) forced a ~170-reg cap -> ~1 GB scratch traffic),
// (b) r4's 3-D grid order restored (z=(b,c) slowest -> 72 consecutive blocks
// share a K/V chunk -> L2 temporal locality; no %8 XCD guessing).
// Per-wave math identical to verified r4 kernel (32x32x16 transposed-S).

typedef __bf16 bf16_t;
typedef __bf16 bf16x8 __attribute__((ext_vector_type(8)));
typedef float f32x4 __attribute__((ext_vector_type(4)));
typedef float f32x16 __attribute__((ext_vector_type(16)));
typedef unsigned long long u64;

#define MFMA16(a, b, c) __builtin_amdgcn_mfma_f32_16x16x32_bf16((a), (b), (c), 0, 0, 0)
#define MFMA32(a, b, c) __builtin_amdgcn_mfma_f32_32x32x16_bf16((a), (b), (c), 0, 0, 0)
#define LOG2E 1.44269504088896340736f
#define SCALE_Q 0.18033688011112042f /* (1/8) * log2(e) */
#define SHIFT_C 8.0f                 /* fixed softmax shift (base-2 units) */
#define NSPLIT 8
#define KCHUNK 1152 /* 9216/8, 18 iters of 64 */

// ---------------- transpose + convert: Wt[n][k] = (bf16)W[k][n], 768x768 ----
__global__ __launch_bounds__(256) void transpose_cvt3(const float* __restrict__ Wq,
                                                      const float* __restrict__ Wk,
                                                      const float* __restrict__ Wv,
                                                      bf16_t* __restrict__ Wt) {
  __shared__ float t[32][33];
  const float* W = (blockIdx.z == 0) ? Wq : (blockIdx.z == 1) ? Wk : Wv;
  bf16_t* o = Wt + (size_t)blockIdx.z * 589824;
  const int bx = blockIdx.x * 32;
  const int by = blockIdx.y * 32;
  const int tx = threadIdx.x, ty = threadIdx.y;
#pragma unroll
  for (int i = 0; i < 32; i += 8) t[ty + i][tx] = W[(bx + ty + i) * 768 + by + tx];
  __syncthreads();
#pragma unroll
  for (int i = 0; i < 32; i += 8)
    o[(by + ty + i) * 768 + bx + tx] = (bf16_t)t[tx][ty + i];
}

// ---------------- canonical C[M][N] = A[M][K] * B[N][K]^T, bf16 MFMA --------
__device__ __forceinline__ bf16x8 cvt8u(const uint4 x, const uint4 y) {
  union { uint4 u; float f[4]; } a, b;
  a.u = x; b.u = y;
  bf16x8 o;
  o[0] = (bf16_t)a.f[0]; o[1] = (bf16_t)a.f[1];
  o[2] = (bf16_t)a.f[2]; o[3] = (bf16_t)a.f[3];
  o[4] = (bf16_t)b.f[0]; o[5] = (bf16_t)b.f[1];
  o[6] = (bf16_t)b.f[2]; o[7] = (bf16_t)b.f[3];
  return o;
}

// Double-buffered LDS, one barrier per 64-deep K slab, register prefetch.
template <int BM, int BN, bool AF32, bool BF32, typename EPI>
__device__ __forceinline__ void gemm_core(char* __restrict__ smem,
                                          const void* __restrict__ Ap, int lda,
                                          const void* __restrict__ Bp, int ldb,
                                          int K, int m0, int n0, EPI epi) {
  constexpr int MT = BM / 32;
  constexpr int NT = BN / 32;
  constexpr int AC = BM * 8 / 256;  // 16B chunks per thread (A)
  constexpr int BC = BN * 8 / 256;
  constexpr int HALF = (BM + BN) * 144;

  const int tid = threadIdx.x;
  const int lane = tid & 63;
  const int w = tid >> 6;
  const int l15 = lane & 15, quad = lane >> 4;
  const int wm = (w & 1) * (BM / 2);
  const int wn = (w >> 1) * (BN / 2);

  uint4 pa[AC][2], pb[BC][2];

  auto loadA = [&](int kk) {
#pragma unroll
    for (int i = 0; i < AC; ++i) {
      const int cidx = tid + i * 256, r = cidx >> 3, ch = cidx & 7;
      if constexpr (AF32) {
        const float* s = (const float*)Ap + (size_t)(m0 + r) * lda + kk + ch * 8;
        pa[i][0] = *(const uint4*)s;
        pa[i][1] = *(const uint4*)(s + 4);
      } else {
        const bf16_t* s = (const bf16_t*)Ap + (size_t)(m0 + r) * lda + kk + ch * 8;
        pa[i][0] = *(const uint4*)s;
      }
    }
  };
  auto loadB = [&](int kk) {
#pragma unroll
    for (int i = 0; i < BC; ++i) {
      const int cidx = tid + i * 256, r = cidx >> 3, ch = cidx & 7;
      if constexpr (BF32) {
        const float* s = (const float*)Bp + (size_t)(n0 + r) * ldb + kk + ch * 8;
        pb[i][0] = *(const uint4*)s;
        pb[i][1] = *(const uint4*)(s + 4);
      } else {
        const bf16_t* s = (const bf16_t*)Bp + (size_t)(n0 + r) * ldb + kk + ch * 8;
        pb[i][0] = *(const uint4*)s;
      }
    }
  };
  auto store = [&](char* base) {
    char* sA = base;
    char* sB = base + BM * 144;
#pragma unroll
    for (int i = 0; i < AC; ++i) {
      const int cidx = tid + i * 256, r = cidx >> 3, ch = cidx & 7;
      if constexpr (AF32)
        *(bf16x8*)(sA + r * 144 + ch * 16) = cvt8u(pa[i][0], pa[i][1]);
      else
        *(uint4*)(sA + r * 144 + ch * 16) = pa[i][0];
    }
#pragma unroll
    for (int i = 0; i < BC; ++i) {
      const int cidx = tid + i * 256, r = cidx >> 3, ch = cidx & 7;
      if constexpr (BF32)
        *(bf16x8*)(sB + r * 144 + ch * 16) = cvt8u(pb[i][0], pb[i][1]);
      else
        *(uint4*)(sB + r * 144 + ch * 16) = pb[i][0];
    }
  };

  const f32x4 fzero = {0.f, 0.f, 0.f, 0.f};
  f32x4 acc[MT][NT];
#pragma unroll
  for (int i = 0; i < MT; ++i)
#pragma unroll
    for (int j = 0; j < NT; ++j) acc[i][j] = fzero;

  const int NS = K / 64;
  loadA(0);
  loadB(0);
  store(smem);

  for (int t = 0; t < NS; ++t) {
    char* base = smem + (t & 1) * HALF;
    char* sA = base;
    char* sB = base + BM * 144;
    __syncthreads();
    if (t + 1 < NS) {
      loadA((t + 1) * 64);
      loadB((t + 1) * 64);
    }
#pragma unroll
    for (int ks = 0; ks < 2; ++ks) {
      bf16x8 af[MT], bfr[NT];
#pragma unroll
      for (int i = 0; i < MT; ++i)
        af[i] = *(const bf16x8*)(sA + (wm + i * 16 + l15) * 144 + ks * 64 + quad * 16);
#pragma unroll
      for (int j = 0; j < NT; ++j)
        bfr[j] = *(const bf16x8*)(sB + (wn + j * 16 + l15) * 144 + ks * 64 + quad * 16);
#pragma unroll
      for (int i = 0; i < MT; ++i)
#pragma unroll
        for (int j = 0; j < NT; ++j) acc[i][j] = MFMA16(af[i], bfr[j], acc[i][j]);
    }
    if (t + 1 < NS) store(smem + ((t + 1) & 1) * HALF);
  }
#pragma unroll
  for (int i = 0; i < MT; ++i)
#pragma unroll
    for (int j = 0; j < NT; ++j)
#pragma unroll
      for (int p = 0; p < 4; ++p)
        epi(m0 + wm + i * 16 + quad * 4 + p, n0 + wn + j * 16 + l15, acc[i][j][p]);
}

// Merged QKV projections (64x64 tiles, dbuf).
__global__ __launch_bounds__(256) void gemm_qkv(const float* __restrict__ hid,
                                                const bf16_t* __restrict__ wT,
                                                const float* __restrict__ bq,
                                                const float* __restrict__ bk,
                                                const float* __restrict__ bv,
                                                bf16_t* __restrict__ q,
                                                bf16_t* __restrict__ ktvt) {
  __shared__ __align__(16) char smem[2 * (64 + 64) * 144];
  if (blockIdx.y < 12) {
    const int m0 = blockIdx.x * 64, n0 = blockIdx.y * 64;
    auto epi = [=](int m, int n, float v) {
      const int b = m / 768, s = m - b * 768;
      const int h = n >> 6, d = n & 63;
      q[((size_t)((b * 12 + h) * 768 + s) << 6) + d] = (bf16_t)((v + bq[n]) * SCALE_Q);
    };
    gemm_core<64, 64, true, false>(smem, hid, 768, wT, 768, 768, m0, n0, epi);
  } else {
    const int m0 = blockIdx.x * 64, n0 = (blockIdx.y - 12) * 64;
    auto epi = [=](int m, int n, float v) {
      const float bias = (m < 768) ? bk[m] : bv[m - 768];
      ktvt[(size_t)m * 1536 + n] = (bf16_t)(v + bias);
    };
    gemm_core<64, 64, false, true>(smem, wT + 589824, 768, hid, 768, 768, m0, n0, epi);
  }
}

// Merged memory GEMMs (64x64 tiles, dbuf).
__global__ __launch_bounds__(256) void gemm_mem(const float* __restrict__ memk,
                                                const float* __restrict__ memv,
                                                const bf16_t* __restrict__ ktvt,
                                                bf16_t* __restrict__ kc,
                                                bf16_t* __restrict__ vct) {
  __shared__ __align__(16) char smem[2 * (64 + 64) * 144];
  const int z = blockIdx.z, b = z / 12, h = z - (z / 12) * 12;
  if (blockIdx.y == 0) {
    const int m0 = blockIdx.x * 64;
    const float* A = memk + (size_t)h * 589824;
    const bf16_t* B = ktvt + (size_t)(h * 64) * 1536 + b * 768;
    bf16_t* outp = kc + (size_t)b * 589824 + (size_t)h * 768 * 64;
    auto epi = [=](int m, int n, float v) { outp[((size_t)m << 6) + n] = (bf16_t)v; };
    gemm_core<64, 64, true, false>(smem, A, 768, B, 1536, 768, m0, 0, epi);
  } else {
    const int n0 = blockIdx.x * 64;
    const bf16_t* A = ktvt + (size_t)(768 + h * 64) * 1536 + b * 768;
    const float* B = memv + (size_t)h * 589824;
    bf16_t* outp = vct + (size_t)b * 589824 + h * 768;
    auto epi = [=](int m, int n, float v) { outp[(size_t)m * 9216 + n] = (bf16_t)v; };
    gemm_core<64, 64, false, true>(smem, A, 1536, B, 768, 768, 0, n0, epi);
  }
}

// ---------------- flash attention, split-K, 32x32 MFMA, transposed-S -------
// 128-thread blocks (2 waves x 64 q-rows). Grid (6,12,16): x=qt fastest,
// z=(b,c) slowest -> 72 consecutive blocks share a K/V chunk (L2 locality).
// __launch_bounds__(128,2): 256-reg cap, no scratch spill (r5 lesson).
__global__ __launch_bounds__(128, 2) void flash_attn_split(
    const bf16_t* __restrict__ q, const bf16_t* __restrict__ kc,
    const bf16_t* __restrict__ vct, const float* __restrict__ mask,
    float* __restrict__ part_acc, float* __restrict__ part_l) {
  const int qt = blockIdx.x, h = blockIdx.y;
  const int z = blockIdx.z, b = z >> 3, c = z & 7;
  const int tid = threadIdx.x;
  const int w = tid >> 6, lane = tid & 63, l31 = lane & 31, h5 = lane >> 5;

  __shared__ __align__(16) bf16_t kc_s[64 * 72];  // [key][d], 144B rows
  __shared__ __align__(16) bf16_t vt_s[64 * 72];  // [d][key], 144B rows
  __shared__ float w_s[64];

  const bf16_t* kcb = kc + (size_t)b * 589824;
  const bf16_t* vtb = vct + (size_t)b * 589824;
  const float* mkb = mask + b * 9216;

  // Q B-frags, held for the whole kernel
  const int q0 = qt * 128 + w * 64;
  bf16x8 qf[2][4];
#pragma unroll
  for (int nb = 0; nb < 2; ++nb) {
    const bf16_t* qp =
        q + ((size_t)((b * 12 + h) * 768 + q0 + nb * 32 + l31) << 6) + h5 * 8;
#pragma unroll
    for (int kd = 0; kd < 4; ++kd) qf[nb][kd] = *(const bf16x8*)(qp + kd * 16);
  }

  f32x16 o[2][2];
#pragma unroll
  for (int nb = 0; nb < 2; ++nb)
#pragma unroll
    for (int md = 0; md < 2; ++md)
#pragma unroll
      for (int r = 0; r < 16; ++r) o[nb][md][r] = 0.f;
  float rsum[2] = {0.f, 0.f};

  // staging: 1024 16B chunks (512 kc + 512 vt), 8 per thread
  const int k00 = c * KCHUNK;
  uint4 pk[4], pv[4];
#pragma unroll
  for (int i = 0; i < 4; ++i) {
    const int ck = tid + i * 128, r = ck >> 3, ch = ck & 7;
    pk[i] = *(const uint4*)(kcb + ((size_t)(k00 + r) << 6) + ch * 8);
    pv[i] = *(const uint4*)(vtb + (size_t)r * 9216 + k00 + ch * 8);
  }
  float mraw = (tid < 64) ? mkb[k00 + tid] : 0.f;

  for (int t = 0; t < KCHUNK / 64; ++t) {
#pragma unroll
    for (int i = 0; i < 4; ++i) {
      const int ck = tid + i * 128, r = ck >> 3, ch = ck & 7;
      *(uint4*)((char*)kc_s + r * 144 + ch * 16) = pk[i];
      *(uint4*)((char*)vt_s + r * 144 + ch * 16) = pv[i];
    }
    if (tid < 64) w_s[tid] = exp2f(fmaf(mraw, LOG2E, -SHIFT_C));
    __syncthreads();

    if (t + 1 < KCHUNK / 64) {  // prefetch next tile behind compute
      const int k1 = k00 + (t + 1) * 64;
#pragma unroll
      for (int i = 0; i < 4; ++i) {
        const int ck = tid + i * 128, r = ck >> 3, ch = ck & 7;
        pk[i] = *(const uint4*)(kcb + ((size_t)(k1 + r) << 6) + ch * 8);
        pv[i] = *(const uint4*)(vtb + (size_t)r * 9216 + k1 + ch * 8);
      }
      if (tid < 64) mraw = mkb[k1 + tid];
    }

#pragma unroll
    for (int mb = 0; mb < 2; ++mb) {  // 32-key block
      bf16x8 ka[4];
#pragma unroll
      for (int kd = 0; kd < 4; ++kd)
        ka[kd] =
            *(const bf16x8*)((char*)kc_s + (mb * 32 + l31) * 144 + kd * 32 + h5 * 16);
      bf16x8 va[2][2];
#pragma unroll
      for (int md = 0; md < 2; ++md)
#pragma unroll
        for (int tt = 0; tt < 2; ++tt) {
          const char* vp =
              (char*)vt_s + (md * 32 + l31) * 144 + mb * 64 + tt * 32 + h5 * 8;
          union { u64 u[2]; bf16x8 v; } tmp;
          tmp.u[0] = *(const u64*)vp;
          tmp.u[1] = *(const u64*)(vp + 16);
          va[md][tt] = tmp.v;
        }
      float wv[16];
#pragma unroll
      for (int g = 0; g < 4; ++g) {
        const float4 t4 = *(const float4*)(w_s + mb * 32 + h5 * 4 + g * 8);
        wv[g * 4 + 0] = t4.x; wv[g * 4 + 1] = t4.y;
        wv[g * 4 + 2] = t4.z; wv[g * 4 + 3] = t4.w;
      }
#pragma unroll
      for (int nb = 0; nb < 2; ++nb) {
        f32x16 s;
#pragma unroll
        for (int r = 0; r < 16; ++r) s[r] = 0.f;
#pragma unroll
        for (int kd = 0; kd < 4; ++kd) s = MFMA32(ka[kd], qf[nb][kd], s);
        float pw[16];
#pragma unroll
        for (int r = 0; r < 16; ++r) {
          const float pv2 = __builtin_amdgcn_exp2f(s[r]) * wv[r];
          rsum[nb] += pv2;
          pw[r] = pv2;
        }
        bf16x8 pb0, pb1;
#pragma unroll
        for (int j = 0; j < 8; ++j) {
          pb0[j] = (bf16_t)pw[j];
          pb1[j] = (bf16_t)pw[8 + j];
        }
#pragma unroll
        for (int md = 0; md < 2; ++md) {
          o[nb][md] = MFMA32(va[md][0], pb0, o[nb][md]);
          o[nb][md] = MFMA32(va[md][1], pb1, o[nb][md]);
        }
      }
    }
    __syncthreads();
  }

  const float l0 = rsum[0] + __shfl_xor(rsum[0], 32);
  const float l1 = rsum[1] + __shfl_xor(rsum[1], 32);

  const int pidx = ((b * 12 + h) * 6 + qt) * NSPLIT + c;
  float* pacc = part_acc + (size_t)pidx * 8192;
#pragma unroll
  for (int nb = 0; nb < 2; ++nb) {
    const int ql = w * 64 + nb * 32 + l31;
#pragma unroll
    for (int md = 0; md < 2; ++md)
#pragma unroll
      for (int g = 0; g < 4; ++g) {
        float4 v;
        v.x = o[nb][md][g * 4 + 0];
        v.y = o[nb][md][g * 4 + 1];
        v.z = o[nb][md][g * 4 + 2];
        v.w = o[nb][md][g * 4 + 3];
        *(float4*)(pacc + (size_t)ql * 64 + md * 32 + h5 * 4 + g * 8) = v;
      }
  }
  if (h5 == 0) {
    part_l[(size_t)pidx * 128 + w * 64 + l31] = l0;
    part_l[(size_t)pidx * 128 + w * 64 + 32 + l31] = l1;
  }
}

// ---------------- combine split-K partials, normalize, gate, write out -----
__global__ __launch_bounds__(1024) void flash_combine(
    const float* __restrict__ part_acc, const float* __restrict__ part_l,
    const float* __restrict__ gate, float* __restrict__ out) {
  const int qt = blockIdx.x, h = blockIdx.y, b = blockIdx.z;  // grid (6,12,2)
  const int tid = threadIdx.x;
  const int row = tid >> 3, dseg = tid & 7;  // 128 rows, 8 d-elems per thread
  const int base = ((b * 12 + h) * 6 + qt) * NSPLIT;

  float L = 0.f;
#pragma unroll
  for (int ci = 0; ci < NSPLIT; ++ci) L += part_l[(size_t)(base + ci) * 128 + row];

  f32x4 a0 = {0.f, 0.f, 0.f, 0.f}, a1 = {0.f, 0.f, 0.f, 0.f};
#pragma unroll
  for (int ci = 0; ci < NSPLIT; ++ci) {
    const float* p = part_acc + (size_t)(base + ci) * 8192 + row * 64 + dseg * 8;
    const float4 v0 = *(const float4*)p;
    const float4 v1 = *(const float4*)(p + 4);
    a0[0] += v0.x; a0[1] += v0.y; a0[2] += v0.z; a0[3] += v0.w;
    a1[0] += v1.x; a1[1] += v1.y; a1[2] += v1.z; a1[3] += v1.w;
  }
  const float g = 1.f / (1.f + expf(-gate[h]));
  const float sc = g / L;
  float* op =
      out + ((size_t)((b * 768 + qt * 128 + row) * 12 + h) << 6) + dseg * 8;
  float4 w0, w1;
  w0.x = a0[0] * sc; w0.y = a0[1] * sc; w0.z = a0[2] * sc; w0.w = a0[3] * sc;
  w1.x = a1[0] * sc; w1.y = a1[1] * sc; w1.z = a1[2] * sc; w1.w = a1[3] * sc;
  *(float4*)op = w0;
  *(float4*)(op + 4) = w1;
}

extern "C" void kernel_launch(void* const* d_in, const int* in_sizes, int n_in,
                              void* d_out, int out_size, void* d_ws, size_t ws_size,
                              hipStream_t stream) {
  const float* hid  = (const float*)d_in[0];
  const float* mask = (const float*)d_in[1];
  const float* Wq   = (const float*)d_in[2];
  const float* bq   = (const float*)d_in[3];
  const float* Wk   = (const float*)d_in[4];
  const float* bk   = (const float*)d_in[5];
  const float* Wv   = (const float*)d_in[6];
  const float* bv   = (const float*)d_in[7];
  const float* gate = (const float*)d_in[8];
  const float* memk = (const float*)d_in[9];
  const float* memv = (const float*)d_in[10];
  float* out = (float*)d_out;

  // workspace layout (~53.7 MB total, unchanged)
  char* ws = (char*)d_ws;
  bf16_t* wqkvT    = (bf16_t*)(ws);             // [2304][768] bf16
  bf16_t* qb       = (bf16_t*)(ws + 3538944);   // q [2][12][768][64] bf16
  bf16_t* ktvt     = (bf16_t*)(ws + 5898240);   // [1536][1536] bf16
  bf16_t* kcw      = (bf16_t*)(ws + 10616832);  // kc [2][9216][64] bf16
  bf16_t* vct      = (bf16_t*)(ws + 12976128);  // vc^T [2][64][9216] bf16
  float*  part_acc = (float*)(ws + 15335424);   // [1152][128][64] fp32
  float*  part_l   = (float*)(ws + 53084160);   // [1152][128] fp32

  transpose_cvt3<<<dim3(24, 24, 3), dim3(32, 8), 0, stream>>>(Wq, Wk, Wv, wqkvT);
  gemm_qkv<<<dim3(24, 36), 256, 0, stream>>>(hid, wqkvT, bq, bk, bv, qb, ktvt);
  gemm_mem<<<dim3(12, 2, 24), 256, 0, stream>>>(memk, memv, ktvt, kcw, vct);
  flash_attn_split<<<dim3(6, 12, 16), 128, 0, stream>>>(qb, kcw, vct, mask,
                                                        part_acc, part_l);
  flash_combine<<<dim3(6, 12, 2), 1024, 0, stream>>>(part_acc, part_l, gate, out);
}

// Round 7
// 235.273 us; speedup vs baseline: 1.7636x; 1.2413x over previous
//
#include <hip/hip_runtime.h>
#include <hip/hip_bf16.h>

// B=2, S=768, H=768, NH=12, D=64, NKEY=9216. Output fp32 [B][S][NH][D].
// Round 7: flash staging moved to global_load_lds (16B DMA, zero staging
// VGPRs -> kills the r5/r6 scratch spill) with XOR source-swizzle replacing
// the 144B row padding (DMA needs lane-contiguous LDS). Double-buffered
// tiles, one barrier/tile. Mask weights for the whole 1152-key chunk
// precomputed once into LDS. Per-wave MFMA math identical to verified r4.

typedef __bf16 bf16_t;
typedef __bf16 bf16x8 __attribute__((ext_vector_type(8)));
typedef float f32x4 __attribute__((ext_vector_type(4)));
typedef float f32x16 __attribute__((ext_vector_type(16)));
typedef unsigned long long u64;

#define MFMA16(a, b, c) __builtin_amdgcn_mfma_f32_16x16x32_bf16((a), (b), (c), 0, 0, 0)
#define MFMA32(a, b, c) __builtin_amdgcn_mfma_f32_32x32x16_bf16((a), (b), (c), 0, 0, 0)
#define LOG2E 1.44269504088896340736f
#define SCALE_Q 0.18033688011112042f /* (1/8) * log2(e) */
#define SHIFT_C 8.0f                 /* fixed softmax shift (base-2 units) */
#define NSPLIT 8
#define KCHUNK 1152 /* 9216/8, 18 iters of 64 */

typedef __attribute__((address_space(3))) unsigned int lds_uint;
typedef const __attribute__((address_space(1))) unsigned int glob_uint;
__device__ __forceinline__ void async_copy16(const void* g, void* l) {
  __builtin_amdgcn_global_load_lds((glob_uint*)g, (lds_uint*)l, 16, 0, 0);
}

// ---------------- transpose + convert: Wt[n][k] = (bf16)W[k][n], 768x768 ----
__global__ __launch_bounds__(256) void transpose_cvt3(const float* __restrict__ Wq,
                                                      const float* __restrict__ Wk,
                                                      const float* __restrict__ Wv,
                                                      bf16_t* __restrict__ Wt) {
  __shared__ float t[32][33];
  const float* W = (blockIdx.z == 0) ? Wq : (blockIdx.z == 1) ? Wk : Wv;
  bf16_t* o = Wt + (size_t)blockIdx.z * 589824;
  const int bx = blockIdx.x * 32;
  const int by = blockIdx.y * 32;
  const int tx = threadIdx.x, ty = threadIdx.y;
#pragma unroll
  for (int i = 0; i < 32; i += 8) t[ty + i][tx] = W[(bx + ty + i) * 768 + by + tx];
  __syncthreads();
#pragma unroll
  for (int i = 0; i < 32; i += 8)
    o[(by + ty + i) * 768 + bx + tx] = (bf16_t)t[tx][ty + i];
}

// ---------------- canonical C[M][N] = A[M][K] * B[N][K]^T, bf16 MFMA --------
__device__ __forceinline__ bf16x8 cvt8u(const uint4 x, const uint4 y) {
  union { uint4 u; float f[4]; } a, b;
  a.u = x; b.u = y;
  bf16x8 o;
  o[0] = (bf16_t)a.f[0]; o[1] = (bf16_t)a.f[1];
  o[2] = (bf16_t)a.f[2]; o[3] = (bf16_t)a.f[3];
  o[4] = (bf16_t)b.f[0]; o[5] = (bf16_t)b.f[1];
  o[6] = (bf16_t)b.f[2]; o[7] = (bf16_t)b.f[3];
  return o;
}

// Double-buffered LDS, one barrier per 64-deep K slab, register prefetch.
template <int BM, int BN, bool AF32, bool BF32, typename EPI>
__device__ __forceinline__ void gemm_core(char* __restrict__ smem,
                                          const void* __restrict__ Ap, int lda,
                                          const void* __restrict__ Bp, int ldb,
                                          int K, int m0, int n0, EPI epi) {
  constexpr int MT = BM / 32;
  constexpr int NT = BN / 32;
  constexpr int AC = BM * 8 / 256;  // 16B chunks per thread (A)
  constexpr int BC = BN * 8 / 256;
  constexpr int HALF = (BM + BN) * 144;

  const int tid = threadIdx.x;
  const int lane = tid & 63;
  const int w = tid >> 6;
  const int l15 = lane & 15, quad = lane >> 4;
  const int wm = (w & 1) * (BM / 2);
  const int wn = (w >> 1) * (BN / 2);

  uint4 pa[AC][2], pb[BC][2];

  auto loadA = [&](int kk) {
#pragma unroll
    for (int i = 0; i < AC; ++i) {
      const int cidx = tid + i * 256, r = cidx >> 3, ch = cidx & 7;
      if constexpr (AF32) {
        const float* s = (const float*)Ap + (size_t)(m0 + r) * lda + kk + ch * 8;
        pa[i][0] = *(const uint4*)s;
        pa[i][1] = *(const uint4*)(s + 4);
      } else {
        const bf16_t* s = (const bf16_t*)Ap + (size_t)(m0 + r) * lda + kk + ch * 8;
        pa[i][0] = *(const uint4*)s;
      }
    }
  };
  auto loadB = [&](int kk) {
#pragma unroll
    for (int i = 0; i < BC; ++i) {
      const int cidx = tid + i * 256, r = cidx >> 3, ch = cidx & 7;
      if constexpr (BF32) {
        const float* s = (const float*)Bp + (size_t)(n0 + r) * ldb + kk + ch * 8;
        pb[i][0] = *(const uint4*)s;
        pb[i][1] = *(const uint4*)(s + 4);
      } else {
        const bf16_t* s = (const bf16_t*)Bp + (size_t)(n0 + r) * ldb + kk + ch * 8;
        pb[i][0] = *(const uint4*)s;
      }
    }
  };
  auto store = [&](char* base) {
    char* sA = base;
    char* sB = base + BM * 144;
#pragma unroll
    for (int i = 0; i < AC; ++i) {
      const int cidx = tid + i * 256, r = cidx >> 3, ch = cidx & 7;
      if constexpr (AF32)
        *(bf16x8*)(sA + r * 144 + ch * 16) = cvt8u(pa[i][0], pa[i][1]);
      else
        *(uint4*)(sA + r * 144 + ch * 16) = pa[i][0];
    }
#pragma unroll
    for (int i = 0; i < BC; ++i) {
      const int cidx = tid + i * 256, r = cidx >> 3, ch = cidx & 7;
      if constexpr (BF32)
        *(bf16x8*)(sB + r * 144 + ch * 16) = cvt8u(pb[i][0], pb[i][1]);
      else
        *(uint4*)(sB + r * 144 + ch * 16) = pb[i][0];
    }
  };

  const f32x4 fzero = {0.f, 0.f, 0.f, 0.f};
  f32x4 acc[MT][NT];
#pragma unroll
  for (int i = 0; i < MT; ++i)
#pragma unroll
    for (int j = 0; j < NT; ++j) acc[i][j] = fzero;

  const int NS = K / 64;
  loadA(0);
  loadB(0);
  store(smem);

  for (int t = 0; t < NS; ++t) {
    char* base = smem + (t & 1) * HALF;
    char* sA = base;
    char* sB = base + BM * 144;
    __syncthreads();
    if (t + 1 < NS) {
      loadA((t + 1) * 64);
      loadB((t + 1) * 64);
    }
#pragma unroll
    for (int ks = 0; ks < 2; ++ks) {
      bf16x8 af[MT], bfr[NT];
#pragma unroll
      for (int i = 0; i < MT; ++i)
        af[i] = *(const bf16x8*)(sA + (wm + i * 16 + l15) * 144 + ks * 64 + quad * 16);
#pragma unroll
      for (int j = 0; j < NT; ++j)
        bfr[j] = *(const bf16x8*)(sB + (wn + j * 16 + l15) * 144 + ks * 64 + quad * 16);
#pragma unroll
      for (int i = 0; i < MT; ++i)
#pragma unroll
        for (int j = 0; j < NT; ++j) acc[i][j] = MFMA16(af[i], bfr[j], acc[i][j]);
    }
    if (t + 1 < NS) store(smem + ((t + 1) & 1) * HALF);
  }
#pragma unroll
  for (int i = 0; i < MT; ++i)
#pragma unroll
    for (int j = 0; j < NT; ++j)
#pragma unroll
      for (int p = 0; p < 4; ++p)
        epi(m0 + wm + i * 16 + quad * 4 + p, n0 + wn + j * 16 + l15, acc[i][j][p]);
}

// Merged QKV projections (64x64 tiles, dbuf).
__global__ __launch_bounds__(256) void gemm_qkv(const float* __restrict__ hid,
                                                const bf16_t* __restrict__ wT,
                                                const float* __restrict__ bq,
                                                const float* __restrict__ bk,
                                                const float* __restrict__ bv,
                                                bf16_t* __restrict__ q,
                                                bf16_t* __restrict__ ktvt) {
  __shared__ __align__(16) char smem[2 * (64 + 64) * 144];
  if (blockIdx.y < 12) {
    const int m0 = blockIdx.x * 64, n0 = blockIdx.y * 64;
    auto epi = [=](int m, int n, float v) {
      const int b = m / 768, s = m - b * 768;
      const int h = n >> 6, d = n & 63;
      q[((size_t)((b * 12 + h) * 768 + s) << 6) + d] = (bf16_t)((v + bq[n]) * SCALE_Q);
    };
    gemm_core<64, 64, true, false>(smem, hid, 768, wT, 768, 768, m0, n0, epi);
  } else {
    const int m0 = blockIdx.x * 64, n0 = (blockIdx.y - 12) * 64;
    auto epi = [=](int m, int n, float v) {
      const float bias = (m < 768) ? bk[m] : bv[m - 768];
      ktvt[(size_t)m * 1536 + n] = (bf16_t)(v + bias);
    };
    gemm_core<64, 64, false, true>(smem, wT + 589824, 768, hid, 768, 768, m0, n0, epi);
  }
}

// Merged memory GEMMs (64x64 tiles, dbuf).
__global__ __launch_bounds__(256) void gemm_mem(const float* __restrict__ memk,
                                                const float* __restrict__ memv,
                                                const bf16_t* __restrict__ ktvt,
                                                bf16_t* __restrict__ kc,
                                                bf16_t* __restrict__ vct) {
  __shared__ __align__(16) char smem[2 * (64 + 64) * 144];
  const int z = blockIdx.z, b = z / 12, h = z - (z / 12) * 12;
  if (blockIdx.y == 0) {
    const int m0 = blockIdx.x * 64;
    const float* A = memk + (size_t)h * 589824;
    const bf16_t* B = ktvt + (size_t)(h * 64) * 1536 + b * 768;
    bf16_t* outp = kc + (size_t)b * 589824 + (size_t)h * 768 * 64;
    auto epi = [=](int m, int n, float v) { outp[((size_t)m << 6) + n] = (bf16_t)v; };
    gemm_core<64, 64, true, false>(smem, A, 768, B, 1536, 768, m0, 0, epi);
  } else {
    const int n0 = blockIdx.x * 64;
    const bf16_t* A = ktvt + (size_t)(768 + h * 64) * 1536 + b * 768;
    const float* B = memv + (size_t)h * 589824;
    bf16_t* outp = vct + (size_t)b * 589824 + h * 768;
    auto epi = [=](int m, int n, float v) { outp[(size_t)m * 9216 + n] = (bf16_t)v; };
    gemm_core<64, 64, false, true>(smem, A, 1536, B, 768, 768, 0, n0, epi);
  }
}

// ---------------- flash attention, split-K, 32x32 MFMA, transposed-S -------
// 128-thread blocks (2 waves x 64 q-rows). Grid (6,12,16), z=(b,c) slowest.
// Staging via global_load_lds DMA (no VGPRs), XOR source-swizzle:
//   LDS position (row, pc) holds global chunk gc = pc ^ (row&7); 128B rows.
// Readers apply the same XOR. Wave 0 stages Kc, wave 1 V^T. Double-buffered.
__global__ __launch_bounds__(128, 2) void flash_attn_split(
    const bf16_t* __restrict__ q, const bf16_t* __restrict__ kc,
    const bf16_t* __restrict__ vct, const float* __restrict__ mask,
    float* __restrict__ part_acc, float* __restrict__ part_l) {
  const int qt = blockIdx.x, h = blockIdx.y;
  const int z = blockIdx.z, b = z >> 3, c = z & 7;
  const int tid = threadIdx.x;
  const int w = tid >> 6, lane = tid & 63, l31 = lane & 31, h5 = lane >> 5;

  __shared__ __align__(16) bf16_t kc_s[2][64 * 64];  // [buf][row*64+..], 128B rows
  __shared__ __align__(16) bf16_t vt_s[2][64 * 64];
  __shared__ float w_all[KCHUNK];                    // mask weights, whole chunk

  const bf16_t* kcb = kc + (size_t)b * 589824;
  const bf16_t* vtb = vct + (size_t)b * 589824;
  const float* mkb = mask + b * 9216;
  const int k00 = c * KCHUNK;

  // Q B-frags, held for the whole kernel
  const int q0 = qt * 128 + w * 64;
  bf16x8 qf[2][4];
#pragma unroll
  for (int nb = 0; nb < 2; ++nb) {
    const bf16_t* qp =
        q + ((size_t)((b * 12 + h) * 768 + q0 + nb * 32 + l31) << 6) + h5 * 8;
#pragma unroll
    for (int kd = 0; kd < 4; ++kd) qf[nb][kd] = *(const bf16x8*)(qp + kd * 16);
  }

  // mask weights for the whole 1152-key chunk, once
  for (int i = tid; i < KCHUNK; i += 128)
    w_all[i] = exp2f(fmaf(mkb[k00 + i], LOG2E, -SHIFT_C));

  // async staging: wave 0 -> kc tile, wave 1 -> vt tile (8 DMA issues each)
  auto stage = [&](int t, int buf) {
    const int k0 = k00 + t * 64;
#pragma unroll
    for (int i = 0; i < 8; ++i) {
      const int p = i * 64 + lane;   // LDS 16B-chunk position
      const int r = p >> 3;          // row 0..63
      const int gc = (p & 7) ^ (r & 7);
      if (w == 0)
        async_copy16(kcb + ((size_t)(k0 + r) << 6) + gc * 8,
                     (char*)&kc_s[buf][0] + p * 16);
      else
        async_copy16(vtb + (size_t)r * 9216 + k0 + gc * 8,
                     (char*)&vt_s[buf][0] + p * 16);
    }
  };

  stage(0, 0);

  f32x16 o[2][2];
#pragma unroll
  for (int nb = 0; nb < 2; ++nb)
#pragma unroll
    for (int md = 0; md < 2; ++md)
#pragma unroll
      for (int r = 0; r < 16; ++r) o[nb][md][r] = 0.f;
  float rsum[2] = {0.f, 0.f};

  for (int t = 0; t < KCHUNK / 64; ++t) {
    const int cur = t & 1;
    __syncthreads();  // drains DMA for buf[cur] (+ w_all on t=0)
    if (t + 1 < KCHUNK / 64) stage(t + 1, cur ^ 1);

    const char* kcS = (const char*)&kc_s[cur][0];
    const char* vtS = (const char*)&vt_s[cur][0];
    const float* wt = w_all + t * 64;

#pragma unroll
    for (int mb = 0; mb < 2; ++mb) {  // 32-key block
      bf16x8 ka[4];
#pragma unroll
      for (int kd = 0; kd < 4; ++kd) {
        const int r = mb * 32 + l31;
        const int cc = (kd * 2 + h5) ^ (r & 7);
        ka[kd] = *(const bf16x8*)(kcS + r * 128 + cc * 16);
      }
      bf16x8 va[2][2];
#pragma unroll
      for (int md = 0; md < 2; ++md)
#pragma unroll
        for (int tt = 0; tt < 2; ++tt) {
          const int r = md * 32 + l31;
          const int c0 = mb * 4 + tt * 2;
          const char* vb = vtS + r * 128 + h5 * 8;
          union { u64 u[2]; bf16x8 v; } tmp;
          tmp.u[0] = *(const u64*)(vb + ((c0 ^ (r & 7)) << 4));
          tmp.u[1] = *(const u64*)(vb + (((c0 + 1) ^ (r & 7)) << 4));
          va[md][tt] = tmp.v;
        }
      float wv[16];
#pragma unroll
      for (int g = 0; g < 4; ++g) {
        const float4 t4 = *(const float4*)(wt + mb * 32 + h5 * 4 + g * 8);
        wv[g * 4 + 0] = t4.x; wv[g * 4 + 1] = t4.y;
        wv[g * 4 + 2] = t4.z; wv[g * 4 + 3] = t4.w;
      }
#pragma unroll
      for (int nb = 0; nb < 2; ++nb) {
        f32x16 s;
#pragma unroll
        for (int r = 0; r < 16; ++r) s[r] = 0.f;
#pragma unroll
        for (int kd = 0; kd < 4; ++kd) s = MFMA32(ka[kd], qf[nb][kd], s);
        float pw[16];
#pragma unroll
        for (int r = 0; r < 16; ++r) {
          const float pv2 = __builtin_amdgcn_exp2f(s[r]) * wv[r];
          rsum[nb] += pv2;
          pw[r] = pv2;
        }
        bf16x8 pb0, pb1;
#pragma unroll
        for (int j = 0; j < 8; ++j) {
          pb0[j] = (bf16_t)pw[j];
          pb1[j] = (bf16_t)pw[8 + j];
        }
#pragma unroll
        for (int md = 0; md < 2; ++md) {
          o[nb][md] = MFMA32(va[md][0], pb0, o[nb][md]);
          o[nb][md] = MFMA32(va[md][1], pb1, o[nb][md]);
        }
      }
    }
  }

  const float l0 = rsum[0] + __shfl_xor(rsum[0], 32);
  const float l1 = rsum[1] + __shfl_xor(rsum[1], 32);

  const int pidx = ((b * 12 + h) * 6 + qt) * NSPLIT + c;
  float* pacc = part_acc + (size_t)pidx * 8192;
#pragma unroll
  for (int nb = 0; nb < 2; ++nb) {
    const int ql = w * 64 + nb * 32 + l31;
#pragma unroll
    for (int md = 0; md < 2; ++md)
#pragma unroll
      for (int g = 0; g < 4; ++g) {
        float4 v;
        v.x = o[nb][md][g * 4 + 0];
        v.y = o[nb][md][g * 4 + 1];
        v.z = o[nb][md][g * 4 + 2];
        v.w = o[nb][md][g * 4 + 3];
        *(float4*)(pacc + (size_t)ql * 64 + md * 32 + h5 * 4 + g * 8) = v;
      }
  }
  if (h5 == 0) {
    part_l[(size_t)pidx * 128 + w * 64 + l31] = l0;
    part_l[(size_t)pidx * 128 + w * 64 + 32 + l31] = l1;
  }
}

// ---------------- combine split-K partials, normalize, gate, write out -----
__global__ __launch_bounds__(1024) void flash_combine(
    const float* __restrict__ part_acc, const float* __restrict__ part_l,
    const float* __restrict__ gate, float* __restrict__ out) {
  const int qt = blockIdx.x, h = blockIdx.y, b = blockIdx.z;  // grid (6,12,2)
  const int tid = threadIdx.x;
  const int row = tid >> 3, dseg = tid & 7;  // 128 rows, 8 d-elems per thread
  const int base = ((b * 12 + h) * 6 + qt) * NSPLIT;

  float L = 0.f;
#pragma unroll
  for (int ci = 0; ci < NSPLIT; ++ci) L += part_l[(size_t)(base + ci) * 128 + row];

  f32x4 a0 = {0.f, 0.f, 0.f, 0.f}, a1 = {0.f, 0.f, 0.f, 0.f};
#pragma unroll
  for (int ci = 0; ci < NSPLIT; ++ci) {
    const float* p = part_acc + (size_t)(base + ci) * 8192 + row * 64 + dseg * 8;
    const float4 v0 = *(const float4*)p;
    const float4 v1 = *(const float4*)(p + 4);
    a0[0] += v0.x; a0[1] += v0.y; a0[2] += v0.z; a0[3] += v0.w;
    a1[0] += v1.x; a1[1] += v1.y; a1[2] += v1.z; a1[3] += v1.w;
  }
  const float g = 1.f / (1.f + expf(-gate[h]));
  const float sc = g / L;
  float* op =
      out + ((size_t)((b * 768 + qt * 128 + row) * 12 + h) << 6) + dseg * 8;
  float4 w0, w1;
  w0.x = a0[0] * sc; w0.y = a0[1] * sc; w0.z = a0[2] * sc; w0.w = a0[3] * sc;
  w1.x = a1[0] * sc; w1.y = a1[1] * sc; w1.z = a1[2] * sc; w1.w = a1[3] * sc;
  *(float4*)op = w0;
  *(float4*)(op + 4) = w1;
}

extern "C" void kernel_launch(void* const* d_in, const int* in_sizes, int n_in,
                              void* d_out, int out_size, void* d_ws, size_t ws_size,
                              hipStream_t stream) {
  const float* hid  = (const float*)d_in[0];
  const float* mask = (const float*)d_in[1];
  const float* Wq   = (const float*)d_in[2];
  const float* bq   = (const float*)d_in[3];
  const float* Wk   = (const float*)d_in[4];
  const float* bk   = (const float*)d_in[5];
  const float* Wv   = (const float*)d_in[6];
  const float* bv   = (const float*)d_in[7];
  const float* gate = (const float*)d_in[8];
  const float* memk = (const float*)d_in[9];
  const float* memv = (const float*)d_in[10];
  float* out = (float*)d_out;

  // workspace layout (~53.7 MB total, unchanged)
  char* ws = (char*)d_ws;
  bf16_t* wqkvT    = (bf16_t*)(ws);             // [2304][768] bf16
  bf16_t* qb       = (bf16_t*)(ws + 3538944);   // q [2][12][768][64] bf16
  bf16_t* ktvt     = (bf16_t*)(ws + 5898240);   // [1536][1536] bf16
  bf16_t* kcw      = (bf16_t*)(ws + 10616832);  // kc [2][9216][64] bf16
  bf16_t* vct      = (bf16_t*)(ws + 12976128);  // vc^T [2][64][9216] bf16
  float*  part_acc = (float*)(ws + 15335424);   // [1152][128][64] fp32
  float*  part_l   = (float*)(ws + 53084160);   // [1152][128] fp32

  transpose_cvt3<<<dim3(24, 24, 3), dim3(32, 8), 0, stream>>>(Wq, Wk, Wv, wqkvT);
  gemm_qkv<<<dim3(24, 36), 256, 0, stream>>>(hid, wqkvT, bq, bk, bv, qb, ktvt);
  gemm_mem<<<dim3(12, 2, 24), 256, 0, stream>>>(memk, memv, ktvt, kcw, vct);
  flash_attn_split<<<dim3(6, 12, 16), 128, 0, stream>>>(qb, kcw, vct, mask,
                                                        part_acc, part_l);
  flash_combine<<<dim3(6, 12, 2), 1024, 0, stream>>>(part_acc, part_l, gate, out);
}